// Round 14
// baseline (271.498 us; speedup 1.0000x reference)
//
#include <hip/hip_runtime.h>
#include <hip/hip_bf16.h>

#define NT   32768
#define NH   2048
#define NE   128
#define TOPK 8
#define BTOK 128             // tokens per block
#define BND    6.0e-4f
#define TWO_B  (2.0f * BND)

// ws layout (bytes):
//   [0,64):          u32 flagged-token counter
//   [64, 64+1MB):    Wt: B-fragment-ordered split-bf16 W (16B chunk g: lane=g&63,
//                    te=(g>>6)&7, s=(g>>9)&1, k32=g>>10)
//   [64+1MB, ...):   records, 32B each: u32 token, u32 cnt, 16x u8 cand ids
#define WS_W_OFF   64
#define WS_REC_U32 262160     // (64 + 1MB)/4

typedef __attribute__((ext_vector_type(8))) short bf16x8;
typedef __attribute__((ext_vector_type(4))) float f32x4;
typedef __attribute__((ext_vector_type(4))) unsigned int u32x4;

static __device__ __forceinline__ unsigned short f2bf(float f) {
    __hip_bfloat16 h = __float2bfloat16(f);
    return *reinterpret_cast<unsigned short*>(&h);
}

// ---------------- K0: build B-fragment-ordered W hi/lo chunks (RNE split) ----------------
__global__ __launch_bounds__(256) void prep_w_kernel(
    const float* __restrict__ W, unsigned short* __restrict__ Wt)
{
    int g = blockIdx.x * 256 + threadIdx.x;   // 65536 16B-per-lane chunks
    int lane = g & 63;
    int te   = (g >> 6) & 7;
    int s    = (g >> 9) & 1;
    int k32  = g >> 10;
    int row  = te * 16 + (lane & 15);
    int kb   = k32 * 32 + (lane >> 4) * 8;
    const float* src = W + (size_t)row * NH + kb;
    float4 f0 = *(const float4*)src;
    float4 f1 = *(const float4*)(src + 4);
    float f[8] = {f0.x, f0.y, f0.z, f0.w, f1.x, f1.y, f1.z, f1.w};
    bf16x8 o;
    #pragma unroll
    for (int e = 0; e < 8; ++e) {
        unsigned short h = f2bf(f[e]);
        if (s == 0) o[e] = (short)h;
        else {
            float fh = __builtin_bit_cast(float, ((unsigned int)h) << 16);
            o[e] = (short)f2bf(f[e] - fh);
        }
    }
    *(bf16x8*)(Wt + (size_t)g * 8) = o;
}

// ---------------- K1: 128-token fused split-bf16 MFMA GEMM + wave-parallel select ----------------
// 512 thr = 8 waves; wave (g,h): tokens [t0+g*64, +64), K-quarter [h*512, +512).
__global__ __launch_bounds__(512, 1) void router_gemm_kernel(
    const float* __restrict__ X, const unsigned short* __restrict__ Wt,
    float* out, unsigned int* __restrict__ ws)
{
    __shared__ float ps[BTOK * 132];    // 67.6 KB logit matrix [128 tok][128 exp]

    const int tid  = threadIdx.x;
    const int lane = tid & 63;
    const int wv   = tid >> 6;          // 0..7
    const int g    = wv & 1;            // token half
    const int h    = wv >> 1;           // K quarter
    const int l15  = lane & 15, lhi = lane >> 4;
    const int t0   = blockIdx.x * BTOK;

    f32x4 acc[4][8];
    #pragma unroll
    for (int i = 0; i < 4; ++i)
        #pragma unroll
        for (int te = 0; te < 8; ++te) acc[i][te] = (f32x4){0.f, 0.f, 0.f, 0.f};

    const float* xb = X + (size_t)(t0 + g * 64 + l15) * NH + h * 512 + lhi * 8;
    const unsigned short* wq = Wt + (size_t)(h * 16) * 8192 + lane * 8;

    #pragma unroll 2
    for (int kk = 0; kk < 16; ++kk) {
        // A fragments: 4 token-tiles, bit-trick hi/lo split
        bf16x8 ah[4], al[4];
        #pragma unroll
        for (int i = 0; i < 4; ++i) {
            const float* xp = xb + (size_t)i * 16 * NH + kk * 32;
            float4 fa = *(const float4*)xp;
            float4 fb = *(const float4*)(xp + 4);
            float ff[8] = {fa.x, fa.y, fa.z, fa.w, fb.x, fb.y, fb.z, fb.w};
            unsigned int hu[4], lu[4];
            #pragma unroll
            for (int p = 0; p < 4; ++p) {
                unsigned int u0 = __builtin_bit_cast(unsigned int, ff[2 * p]);
                unsigned int u1 = __builtin_bit_cast(unsigned int, ff[2 * p + 1]);
                unsigned int r0 = u0 + 0x8000u, r1 = u1 + 0x8000u;
                hu[p] = (r0 >> 16) | (r1 & 0xFFFF0000u);
                float h0 = __builtin_bit_cast(float, r0 & 0xFFFF0000u);
                float h1 = __builtin_bit_cast(float, r1 & 0xFFFF0000u);
                float e0 = ff[2 * p] - h0, e1 = ff[2 * p + 1] - h1;
                unsigned int s0 = __builtin_bit_cast(unsigned int, e0) + 0x8000u;
                unsigned int s1 = __builtin_bit_cast(unsigned int, e1) + 0x8000u;
                lu[p] = (s0 >> 16) | (s1 & 0xFFFF0000u);
            }
            ah[i] = __builtin_bit_cast(bf16x8, (u32x4){hu[0], hu[1], hu[2], hu[3]});
            al[i] = __builtin_bit_cast(bf16x8, (u32x4){lu[0], lu[1], lu[2], lu[3]});
        }
        // B fragments + MFMA
        const unsigned short* wb = wq + (size_t)kk * 8192;
        #pragma unroll
        for (int te = 0; te < 8; ++te) {
            bf16x8 bh = *(const bf16x8*)(wb + te * 512);
            bf16x8 bl = *(const bf16x8*)(wb + 4096 + te * 512);
            #pragma unroll
            for (int i = 0; i < 4; ++i) {
                acc[i][te] = __builtin_amdgcn_mfma_f32_16x16x32_bf16(ah[i], bh, acc[i][te], 0, 0, 0);
                acc[i][te] = __builtin_amdgcn_mfma_f32_16x16x32_bf16(al[i], bh, acc[i][te], 0, 0, 0);
                acc[i][te] = __builtin_amdgcn_mfma_f32_16x16x32_bf16(ah[i], bl, acc[i][te], 0, 0, 0);
            }
        }
    }

    // ---- cross-wave K reduction into ps[128][132] (4 sequential stages) ----
    #pragma unroll
    for (int s = 0; s < 4; ++s) {
        if (h == s) {
            #pragma unroll
            for (int i = 0; i < 4; ++i)
                #pragma unroll
                for (int te = 0; te < 8; ++te)
                    #pragma unroll
                    for (int q = 0; q < 4; ++q) {
                        int o = (g * 64 + i * 16 + lhi * 4 + q) * 132 + te * 16 + l15;
                        if (s == 0) ps[o] = acc[i][te][q];
                        else        ps[o] += acc[i][te][q];
                    }
        }
        __syncthreads();
    }

    // ---- wave-parallel select: wave wv owns tokens [wv*16, wv*16+16) ----
    for (int j = 0; j < 16; ++j) {
        const int tl = wv * 16 + j;
        const int tg = t0 + tl;
        const float* row = &ps[tl * 132];
        float2 v2 = *(const float2*)(row + lane * 2);
        const float ov0 = v2.x, ov1 = v2.y;
        float v0 = ov0, v1 = ov1;
        const int i0 = lane * 2, i1 = lane * 2 + 1;

        float myv = 0.f; int myi = 0;   // lane k holds rank-k (value, index), k<13
        int r0 = -1, r1 = -1;

        #pragma unroll
        for (int k = 0; k < 13; ++k) {
            float av = v0; int ai = i0;
            if (v1 > av) { av = v1; ai = i1; }     // tie keeps lower index i0
            #pragma unroll
            for (int off = 32; off >= 1; off >>= 1) {
                float qv = __shfl_xor(av, off);
                int   qi = __shfl_xor(ai, off);
                if (qv > av || (qv == av && qi < ai)) { av = qv; ai = qi; }
            }
            if (lane == k) { myv = av; myi = ai; }
            if (k < 8) {
                if (i0 == ai) r0 = k;
                if (i1 == ai) r1 = k;
            }
            if (i0 == ai) v0 = -3.0e38f;
            if (i1 == ai) v1 = -3.0e38f;
        }

        const float top0 = __shfl(myv, 0);
        const float v7   = __shfl(myv, 7);
        const float v12  = __shfl(myv, 12);
        const float nv   = __shfl(myv, lane + 1);

        const bool gap = (lane < 8) && (myv - nv < TWO_B);
        const bool flagged = __any(gap);

        float ksum = (lane < 8) ? expf(myv - top0) : 0.f;
        #pragma unroll
        for (int off = 1; off < 8; off <<= 1) ksum += __shfl_xor(ksum, off);
        ksum = __shfl(ksum, 0);

        float o0 = 0.f, o1 = 0.f;
        if (r0 >= 0) o0 = expf(ov0 - top0) / ksum;
        if (r1 >= 0) o1 = expf(ov1 - top0) / ksum;
        *(float2*)(out + (size_t)tg * NE + lane * 2) = make_float2(o0, o1);

        if (lane < 8)
            out[(size_t)NT * NE + (size_t)tg * TOPK + lane] = (float)myi;

        if (flagged) {
            const float thr = v7 - TWO_B;
            unsigned int cnt;
            if (v12 >= thr) {
                cnt = 0xFFu;
            } else {
                bool inc = (lane < 8) || (lane < 13 && myv >= thr);
                cnt = (unsigned int)__popcll(__ballot(inc) & 0x1FFFull);
            }
            unsigned int wrd0 = 0, wrd1 = 0, wrd2 = 0, wrd3 = 0;
            #pragma unroll
            for (int b = 0; b < 4; ++b) {
                unsigned int id;
                id = (unsigned int)__shfl(myi, 0 + b)  & 255u;
                if ((unsigned int)(0 + b)  < cnt) wrd0 |= id << (8 * b);
                id = (unsigned int)__shfl(myi, 4 + b)  & 255u;
                if ((unsigned int)(4 + b)  < cnt) wrd1 |= id << (8 * b);
                id = (unsigned int)__shfl(myi, 8 + b)  & 255u;
                if ((unsigned int)(8 + b)  < cnt && cnt != 0xFFu) wrd2 |= id << (8 * b);
                id = (unsigned int)__shfl(myi, 12 + b) & 255u;
                if ((unsigned int)(12 + b) < cnt && cnt != 0xFFu) wrd3 |= id << (8 * b);
            }
            if (lane == 0) {
                unsigned int slot = atomicAdd(ws, 1u);
                unsigned int* rec = ws + WS_REC_U32 + slot * 8;
                rec[0] = (unsigned int)tg;
                rec[1] = cnt;
                rec[2] = wrd0; rec[3] = wrd1; rec[4] = wrd2; rec[5] = wrd3;
            }
        }
    }
}

// ---------------- K2: f64 refine flagged tokens ----------------
__global__ __launch_bounds__(256) void finalize_kernel(
    const float* __restrict__ X, const float* __restrict__ W,
    float* __restrict__ out, const unsigned int* __restrict__ ws)
{
    __shared__ float  xs[2048];
    __shared__ double cv[128];
    __shared__ int    cid[128];
    __shared__ float  ovals[8];
    __shared__ int    oidx[8];

    const int tid = threadIdx.x;
    const int lane = tid & 63, w = tid >> 6;
    const unsigned int n = ws[0];

    for (unsigned int rI = blockIdx.x; rI < n; rI += gridDim.x) {
        const unsigned int* rec = ws + WS_REC_U32 + rI * 8;
        const int tg = (int)rec[0];
        const unsigned int cnt = rec[1];
        const unsigned char* ids = (const unsigned char*)(rec + 2);
        const int nc = (cnt == 0xFFu) ? NE : (int)cnt;

        #pragma unroll
        for (int q = 0; q < 2; ++q) {
            int i = tid + q * 256;
            *(float4*)(xs + i * 4) = *(const float4*)(X + (size_t)tg * NH + i * 4);
        }
        __syncthreads();

        for (int c = w; c < nc; c += 4) {
            int e = (cnt == 0xFFu) ? c : (int)ids[c];
            const float* wrow = W + (size_t)e * NH;
            double s = 0.0;
            #pragma unroll
            for (int m = 0; m < 8; ++m) {
                float4 wv = *(const float4*)(wrow + m * 256 + lane * 4);
                float4 xv = *(const float4*)(xs + m * 256 + lane * 4);
                s = fma((double)xv.x, (double)wv.x, s);
                s = fma((double)xv.y, (double)wv.y, s);
                s = fma((double)xv.z, (double)wv.z, s);
                s = fma((double)xv.w, (double)wv.w, s);
            }
            #pragma unroll
            for (int off = 32; off >= 1; off >>= 1) s += __shfl_xor(s, off);
            if (lane == 0) { cv[c] = s; cid[c] = e; }
        }
        __syncthreads();

        if (tid == 0) {
            double lv[8];
            #pragma unroll
            for (int k = 0; k < 8; ++k) {
                double best = -1.0e300; int bi = 1 << 30, bc = 0;
                for (int c = 0; c < nc; ++c) {
                    double v = cv[c]; int e = cid[c];
                    if (v > best || (v == best && e < bi)) { best = v; bi = e; bc = c; }
                }
                lv[k] = best; oidx[k] = bi; cv[bc] = -1.0e301;
            }
            double m = lv[0], sum = 0.0, p[8];
            #pragma unroll
            for (int k = 0; k < 8; ++k) { p[k] = exp(lv[k] - m); sum += p[k]; }
            #pragma unroll
            for (int k = 0; k < 8; ++k) ovals[k] = (float)(p[k] / sum);
        }
        __syncthreads();

        float* srow = out + (size_t)tg * NE;
        if (tid < NE) {
            float val = 0.f;
            #pragma unroll
            for (int k = 0; k < 8; ++k) if (oidx[k] == tid) val = ovals[k];
            srow[tid] = val;
        }
        if (tid < TOPK) out[(size_t)NT * NE + (size_t)tg * TOPK + tid] = (float)oidx[tid];
        __syncthreads();
    }
}

extern "C" void kernel_launch(void* const* d_in, const int* in_sizes, int n_in,
                              void* d_out, int out_size, void* d_ws, size_t ws_size,
                              hipStream_t stream) {
    const float* X = (const float*)d_in[0];
    const float* W = (const float*)d_in[1];
    float* out = (float*)d_out;
    unsigned char* wsb = (unsigned char*)d_ws;
    unsigned short* Wt = (unsigned short*)(wsb + WS_W_OFF);

    hipMemsetAsync(d_ws, 0, 64, stream);
    prep_w_kernel<<<256, 256, 0, stream>>>(W, Wt);
    router_gemm_kernel<<<NT / BTOK, 512, 0, stream>>>(X, Wt, out, (unsigned int*)d_ws);
    finalize_kernel<<<1024, 256, 0, stream>>>(X, W, out, (const unsigned int*)d_ws);
}